// Round 7
// baseline (245.706 us; speedup 1.0000x reference)
//
#include <hip/hip_runtime.h>
#include <hip/hip_bf16.h>

// StrassenMHA on MI355X — round 7: barrier-free main contraction.
// E3 is pre-permuted into MFMA fragment layout (global), E1 transposed,
// V2 transposed -> strassen kernel has NO LDS and NO __syncthreads.
// B=2, N=256, DIM=512, H=8, DH=64. Output f32.

namespace {
constexpr int kN = 256, kH = 8, kDH = 64;
constexpr int kBH = 16;
constexpr int kBN = 512;
constexpr int kDIM = 512;
constexpr int kQKV = 2560;
constexpr float kEps = 1.1920928955078125e-07f;

typedef unsigned short u16;
typedef __attribute__((ext_vector_type(8))) short short8v;   // 8 x bf16
typedef __attribute__((ext_vector_type(4))) float float4v;   // mfma acc

// ws layout (float-element offsets); sizes in float-slots
constexpr size_t OF_XB   = 0;                   // 131,072 (xb bf16 512x512)
constexpr size_t OF_WT   = OF_XB   + 131072;    // 655,360 (w_qkvT bf16 2560x512)
constexpr size_t OF_WOT  = OF_WT   + 655360;    // 131,072 (w_outT bf16 512x512)
constexpr size_t OF_QKVB = OF_WOT  + 131072;    // 655,360 (qkv bf16 512x2560)
constexpr size_t OF_QB   = OF_QKVB + 655360;    // 131,072 (Q bf16 16x256x64)
constexpr size_t OF_K1B  = OF_QB   + 131072;    // 131,072
constexpr size_t OF_K2B  = OF_K1B  + 131072;    // 131,072
constexpr size_t OF_V1   = OF_K2B  + 131072;    // 262,144 f32 [bh][n][d]
constexpr size_t OF_V2T  = OF_V1   + 262144;    // 262,144 f32 [bh][d][k]
constexpr size_t OF_E1T  = OF_V2T  + 262144;    // 1,048,576 f32 [bh][j][i]
constexpr size_t OF_E2B  = OF_E1T  + 1048576;   // 524,288 (bf16 [bh][i][k])
constexpr size_t OF_E3F  = OF_E2B  + 524288;    // 524,288 (bf16 frag-layout)
constexpr size_t OF_NUM  = OF_E3F  + 524288;    // 262,144 f32
constexpr size_t OF_DEN  = OF_NUM  + 262144;    //   4,096 f32
constexpr size_t OF_ATNB = OF_DEN  + 4096;      // 131,072 (attn bf16 512x512)
// total = 4,984,832 floats = 19.94 MB
} // namespace

__device__ __forceinline__ unsigned int bf16_rne(float a) {
  unsigned int u = __float_as_uint(a);
  return (u + 0x7fffu + ((u >> 16) & 1u)) >> 16;
}
__device__ __forceinline__ unsigned int pk2_bf16(float a, float b) {
  unsigned int ua = bf16_rne(a);
  unsigned int ub = __float_as_uint(b);
  ub = (ub + 0x7fffu + ((ub >> 16) & 1u)) & 0xffff0000u;
  return ua | ub;
}
__device__ __forceinline__ float bf2f(u16 v) {
  return __uint_as_float(((unsigned)v) << 16);
}

// ------------------------------------------------------------ f32 -> bf16
__global__ __launch_bounds__(256)
void conv_bf16(const float* __restrict__ in, u16* __restrict__ out) {
  const int id = blockIdx.x * 256 + threadIdx.x;
  float4 v = ((const float4*)in)[id];
  ushort4 o;
  o.x = (u16)bf16_rne(v.x); o.y = (u16)bf16_rne(v.y);
  o.z = (u16)bf16_rne(v.z); o.w = (u16)bf16_rne(v.w);
  ((ushort4*)out)[id] = o;
}

// --------------------------------------------- transpose f32 -> bf16
__global__ __launch_bounds__(256)
void transpose_bf16(const float* __restrict__ in, u16* __restrict__ out,
                    int rows, int cols) {
  __shared__ float tile[32][33];
  const int tx = threadIdx.x & 31, ty8 = threadIdx.x >> 5;
  const int c0 = blockIdx.x * 32, r0 = blockIdx.y * 32;
#pragma unroll
  for (int rr = 0; rr < 4; ++rr) {
    int r = ty8 + rr * 8;
    tile[r][tx] = in[(size_t)(r0 + r) * cols + c0 + tx];
  }
  __syncthreads();
#pragma unroll
  for (int rr = 0; rr < 4; ++rr) {
    int r = ty8 + rr * 8;
    out[(size_t)(c0 + r) * rows + r0 + tx] = (u16)bf16_rne(tile[tx][r]);
  }
}

// --------------------------------------------- bf16 MFMA GEMM, frag-direct
// C[M][N] = A[M][K] @ BT[N][K]^T. grid (N/64, M/64), 256 thr (4 waves m16).
template <bool F32OUT>
__global__ __launch_bounds__(256)
void gemm_mfma(const u16* __restrict__ A, const u16* __restrict__ BT,
               void* __restrict__ C, int M, int N, int K) {
  const int t = threadIdx.x, lane = t & 63, w = t >> 6;
  const int lrow = lane & 15, lk = lane >> 4;
  const int m0 = blockIdx.y * 64 + w * 16;
  const int n0 = blockIdx.x * 64;
  float4v acc[4] = {};
#pragma unroll 4
  for (int kk = 0; kk < K; kk += 32) {
    short8v aF = *(const short8v*)(A + (size_t)(m0 + lrow) * K + kk + lk * 8);
#pragma unroll
    for (int n = 0; n < 4; ++n) {
      short8v bF = *(const short8v*)(BT + (size_t)(n0 + n * 16 + lrow) * K + kk + lk * 8);
      acc[n] = __builtin_amdgcn_mfma_f32_16x16x32_bf16(aF, bF, acc[n], 0, 0, 0);
    }
  }
#pragma unroll
  for (int n = 0; n < 4; ++n)
#pragma unroll
    for (int r = 0; r < 4; ++r) {
      const int row = m0 + lk * 4 + r, col = n0 + n * 16 + lrow;
      if (F32OUT) ((float*)C)[(size_t)row * N + col] = acc[n][r];
      else        ((u16*)C)[(size_t)row * N + col] = (u16)bf16_rne(acc[n][r]);
    }
}

// ------------------------------------------------- RMSNorm + head split
// V2 written TRANSPOSED: V2T[bh][d][k].
__global__ __launch_bounds__(64)
void rms_layout(const u16* __restrict__ qkvb,
                const float* __restrict__ wq, const float* __restrict__ wk1,
                const float* __restrict__ wk2,
                u16* __restrict__ Qb, u16* __restrict__ K1b,
                u16* __restrict__ K2b, float* __restrict__ V1,
                float* __restrict__ V2T) {
  const int bnh = blockIdx.x;
  const int h = bnh & 7;
  const int bn = bnh >> 3;
  const int b = bn >> 8;
  const int d = threadIdx.x;
  const u16* row = qkvb + (size_t)bn * kQKV;
  const int base = h * 64 + d;
  float q  = bf2f(row[0 * 512 + base]);
  float k1 = bf2f(row[1 * 512 + base]);
  float k2 = bf2f(row[2 * 512 + base]);
  float v1 = bf2f(row[3 * 512 + base]);
  float v2 = bf2f(row[4 * 512 + base]);
  float sq = q * q, s1 = k1 * k1, s2 = k2 * k2;
#pragma unroll
  for (int m = 32; m >= 1; m >>= 1) {
    sq += __shfl_xor(sq, m);
    s1 += __shfl_xor(s1, m);
    s2 += __shfl_xor(s2, m);
  }
  const float rq = rsqrtf(sq * (1.0f / 64) + kEps);
  const float r1 = rsqrtf(s1 * (1.0f / 64) + kEps);
  const float r2 = rsqrtf(s2 * (1.0f / 64) + kEps);
  const int bh = b * kH + h;
  const int n = bn & 255;
  const size_t o = ((size_t)bh * kN + n) * kDH + d;
  Qb[o]  = (u16)bf16_rne(q * rq * wq[d]);
  K1b[o] = (u16)bf16_rne(k1 * r1 * wk1[d]);
  K2b[o] = (u16)bf16_rne(k2 * r2 * wk2[d]);
  V1[o] = v1;
  V2T[((size_t)bh * kDH + d) * kN + n] = v2;
}

// --------------------------------- E = exp(clip(dot/8)) via MFMA
// type 0: Q.K1 -> E1T[j][i] (f32, transposed)
// type 1: Q.K2 -> E2b[i][k] (bf16, row-major)
// type 2: K1.K2 -> E3f (bf16, MFMA FRAGMENT layout via LDS repack)
__global__ __launch_bounds__(256)
void sims_mfma(const u16* __restrict__ Qb, const u16* __restrict__ K1b,
               const u16* __restrict__ K2b, float* __restrict__ E1T,
               u16* __restrict__ E2b, u16* __restrict__ E3f) {
  __shared__ __align__(16) u16 Lt[64 * 80];   // 10 KB repack tile (type 2)
  const int bh = blockIdx.x, type = blockIdx.y;
  const int it = blockIdx.z >> 2, jt = blockIdx.z & 3;
  const int t = threadIdx.x, lane = t & 63, w = t >> 6;
  const int lrow = lane & 15, lk = lane >> 4;
  const u16* Ap = (type == 2 ? K1b : Qb) + (size_t)bh * 16384;
  const u16* Bp = (type == 0 ? K1b : K2b) + (size_t)bh * 16384;
  const int i0 = it * 64 + w * 16, j0 = jt * 64;
  float4v acc[4] = {};
#pragma unroll
  for (int kk = 0; kk < 2; ++kk) {
    short8v aF = *(const short8v*)(Ap + (size_t)(i0 + lrow) * 64 + kk * 32 + lk * 8);
#pragma unroll
    for (int n = 0; n < 4; ++n) {
      short8v bF = *(const short8v*)(Bp + (size_t)(j0 + n * 16 + lrow) * 64 + kk * 32 + lk * 8);
      acc[n] = __builtin_amdgcn_mfma_f32_16x16x32_bf16(aF, bF, acc[n], 0, 0, 0);
    }
  }
  if (type == 0) {
    // transposed f32: E1T[j][i]
    float* Ep = E1T + (size_t)bh * 65536;
#pragma unroll
    for (int n = 0; n < 4; ++n)
#pragma unroll
      for (int r = 0; r < 4; ++r) {
        float s = acc[n][r] * 0.125f;
        s = fminf(fmaxf(s, -40.0f), 40.0f);
        Ep[(size_t)(j0 + n * 16 + lrow) * 256 + i0 + lk * 4 + r] = __expf(s);
      }
  } else if (type == 1) {
    u16* Ep = E2b + (size_t)bh * 65536;
#pragma unroll
    for (int n = 0; n < 4; ++n)
#pragma unroll
      for (int r = 0; r < 4; ++r) {
        float s = acc[n][r] * 0.125f;
        s = fminf(fmaxf(s, -40.0f), 40.0f);
        Ep[(size_t)(i0 + lk * 4 + r) * 256 + j0 + n * 16 + lrow] =
            (u16)bf16_rne(__expf(s));
      }
  } else {
    // fragment-layout repack: rows (i = strassen j) x cols (j = strassen k)
#pragma unroll
    for (int n = 0; n < 4; ++n)
#pragma unroll
      for (int r = 0; r < 4; ++r) {
        float s = acc[n][r] * 0.125f;
        s = fminf(fmaxf(s, -40.0f), 40.0f);
        Lt[(w * 16 + lk * 4 + r) * 80 + n * 16 + lrow] = (u16)bf16_rne(__expf(s));
      }
    __syncthreads();
    u16* Ep = E3f + (size_t)bh * 65536;
#pragma unroll
    for (int ss = 0; ss < 2; ++ss) {
      const int sl = ss * 256 + t;
      const int nn = sl >> 7, sub = (sl >> 6) & 1, ln = sl & 63;
      const int lr = ln & 15, lq = ln >> 4;
      const uint4 v = *(const uint4*)&Lt[(nn * 16 + lr) * 80 + sub * 32 + lq * 8];
      const size_t gslot = (size_t)((((it * 4 + nn) * 4 + jt) * 2 + sub) * 64 + ln);
      *(uint4*)(Ep + gslot * 8) = v;
    }
  }
}

// ---------------------------------------------------------- main contraction
// num[i,d] = sum_j e1[i,j] v1[j,d] * sum_k (e2[i,k] v2[k,d]) e3[j,k]
// Barrier-free: no LDS. bF read coalesced from frag-layout E3f (L1/L2).
// grid (16|1, 4, 16): x=dblk, y=iblk, z=bh. 256 thr / 4 waves.
template <bool ISDEN>
__global__ __launch_bounds__(256)
void strassen_v3(const u16* __restrict__ E2b, const float* __restrict__ E1T,
                 const u16* __restrict__ E3f, const float* __restrict__ V1,
                 const float* __restrict__ V2T, float* __restrict__ NUM,
                 float* __restrict__ DEN) {
  constexpr int NDD = ISDEN ? 1 : 4;
  const int dblk = blockIdx.x;
  const int iblk = blockIdx.y;
  const int bh = blockIdx.z;
  const int d0 = dblk * 4;
  const int t = threadIdx.x;
  const int lane = t & 63, w = t >> 6;
  const int lrow = lane & 15, lk = lane >> 4;

  const size_t ebase = (size_t)bh * 65536;
  const u16* e2p = E2b + ebase;
  const float* e1p = E1T + ebase;
  const u16* e3p = E3f + ebase;
  const float* v2p = V2T + ((size_t)bh * kDH + d0) * kN;

  const int irowA = iblk * 64 + w * 16 + lrow;
  const int irowD = iblk * 64 + w * 16 + lk * 4;

  float p[NDD][4] = {};

#pragma unroll 1
  for (int ks = 0; ks < 4; ++ks) {
    // ---- A fragments: e2 (* v2 per d) in registers
    short8v aFd[NDD][2];
#pragma unroll
    for (int sub = 0; sub < 2; ++sub) {
      const int kseg = ks * 64 + sub * 32 + lk * 8;
      const short8v araw = *(const short8v*)(e2p + (size_t)irowA * 256 + kseg);
      if (ISDEN) {
        aFd[0][sub] = araw;
      } else {
        float af[8];
#pragma unroll
        for (int e = 0; e < 8; ++e) af[e] = bf2f((u16)araw[e]);
#pragma unroll
        for (int dd = 0; dd < NDD; ++dd) {
          const float4 va = *(const float4*)(v2p + (size_t)dd * kN + kseg);
          const float4 vb = *(const float4*)(v2p + (size_t)dd * kN + kseg + 4);
          union { short8v s; uint4 u; } pk;
          pk.u.x = pk2_bf16(af[0] * va.x, af[1] * va.y);
          pk.u.y = pk2_bf16(af[2] * va.z, af[3] * va.w);
          pk.u.z = pk2_bf16(af[4] * vb.x, af[5] * vb.y);
          pk.u.w = pk2_bf16(af[6] * vb.z, af[7] * vb.w);
          aFd[dd][sub] = pk.s;
        }
      }
    }
    // ---- j-tiles: per (jt,n) compute acc then fold immediately
#pragma unroll 2
    for (int jt = 0; jt < 4; ++jt) {
#pragma unroll
      for (int n = 0; n < 4; ++n) {
        float4v acc4[NDD] = {};
#pragma unroll
        for (int sub = 0; sub < 2; ++sub) {
          const short8v bF = *(const short8v*)(
              e3p + ((size_t)((((jt * 4 + n) * 4 + ks) * 2 + sub) * 64 + lane)) * 8);
#pragma unroll
          for (int dd = 0; dd < NDD; ++dd)
            acc4[dd] = __builtin_amdgcn_mfma_f32_16x16x32_bf16(
                aFd[dd][sub], bF, acc4[dd], 0, 0, 0);
        }
        const int j = jt * 64 + n * 16 + lrow;
        const float4 e4 = *(const float4*)(e1p + (size_t)j * 256 + irowD);
        const float e1f[4] = {e4.x, e4.y, e4.z, e4.w};
        if (ISDEN) {
#pragma unroll
          for (int r = 0; r < 4; ++r)
            p[0][r] = fmaf(e1f[r], acc4[0][r], p[0][r]);
        } else {
          const float4 v4 = *(const float4*)(V1 + ((size_t)bh * kN + j) * kDH + d0);
          const float v1s[4] = {v4.x, v4.y, v4.z, v4.w};
#pragma unroll
          for (int dd = 0; dd < NDD; ++dd)
#pragma unroll
            for (int r = 0; r < 4; ++r)
              p[dd][r] = fmaf(e1f[r] * v1s[dd], acc4[dd][r], p[dd][r]);
        }
      }
    }
  }

  // reduce the 16 j-residues (across lrow lanes)
#pragma unroll
  for (int dd = 0; dd < NDD; ++dd)
#pragma unroll
    for (int r = 0; r < 4; ++r) {
      float v = p[dd][r];
      v += __shfl_xor(v, 1);
      v += __shfl_xor(v, 2);
      v += __shfl_xor(v, 4);
      v += __shfl_xor(v, 8);
      p[dd][r] = v;
    }
  if (lrow == 0) {
    if (!ISDEN) {
#pragma unroll
      for (int r = 0; r < 4; ++r)
#pragma unroll
        for (int dd = 0; dd < NDD; ++dd)
          NUM[((size_t)bh * kN + irowD + r) * kDH + d0 + dd] = p[dd][r];
    } else {
#pragma unroll
      for (int r = 0; r < 4; ++r)
        DEN[(size_t)bh * kN + irowD + r] = p[0][r];
    }
  }
}

// --------------------------------- normalize + head transpose, bf16 out
__global__ __launch_bounds__(256)
void normalize_attn(const float* __restrict__ NUMp, const float* __restrict__ DENp,
                    u16* __restrict__ attnb) {
  const int idx = blockIdx.x * 256 + threadIdx.x;   // [bh][i][d]
  const int d = idx & 63;
  const int i = (idx >> 6) & 255;
  const int bh = idx >> 14;
  const int b = bh >> 3, h = bh & 7;
  const float v = NUMp[idx] / DENp[bh * kN + i];
  attnb[((size_t)(b * kN + i)) * kDIM + h * kDH + d] = (u16)bf16_rne(v);
}

// ----------------------------------------------------------------- launch
extern "C" void kernel_launch(void* const* d_in, const int* in_sizes, int n_in,
                              void* d_out, int out_size, void* d_ws, size_t ws_size,
                              hipStream_t stream) {
  const float* x     = (const float*)d_in[0];
  const float* w_qkv = (const float*)d_in[1];
  const float* w_out = (const float*)d_in[2];
  const float* qw    = (const float*)d_in[3];
  const float* k1w   = (const float*)d_in[4];
  const float* k2w   = (const float*)d_in[5];

  float* ws = (float*)d_ws;
  u16* xb   = (u16*)(ws + OF_XB);
  u16* wT   = (u16*)(ws + OF_WT);
  u16* woT  = (u16*)(ws + OF_WOT);
  u16* qkvb = (u16*)(ws + OF_QKVB);
  u16* Qb   = (u16*)(ws + OF_QB);
  u16* K1b  = (u16*)(ws + OF_K1B);
  u16* K2b  = (u16*)(ws + OF_K2B);
  float* V1 = ws + OF_V1;
  float* V2T = ws + OF_V2T;
  float* E1T = ws + OF_E1T;
  u16* E2b  = (u16*)(ws + OF_E2B);
  u16* E3f  = (u16*)(ws + OF_E3F);
  float* NUMp = ws + OF_NUM;
  float* DENp = ws + OF_DEN;
  u16* atnb = (u16*)(ws + OF_ATNB);

  // 0) dtype prep: x -> bf16; w_qkv, w_out -> transposed bf16
  conv_bf16<<<dim3(kBN * kDIM / 1024), 256, 0, stream>>>(x, xb);
  transpose_bf16<<<dim3(kQKV / 32, kDIM / 32), 256, 0, stream>>>(
      w_qkv, wT, kDIM, kQKV);
  transpose_bf16<<<dim3(kDIM / 32, kDIM / 32), 256, 0, stream>>>(
      w_out, woT, kDIM, kDIM);

  // 1) qkv = x @ w_qkv (bf16 MFMA, bf16 out)
  gemm_mfma<false><<<dim3(kQKV / 64, kBN / 64), 256, 0, stream>>>(
      xb, wT, qkvb, kBN, kQKV, kDIM);

  // 2) rmsnorm + head split (V2 transposed)
  rms_layout<<<dim3(kBN * kH), 64, 0, stream>>>(
      qkvb, qw, k1w, k2w, Qb, K1b, K2b, V1, V2T);

  // 3) E1T (f32,T), E2 (bf16), E3f (bf16 frag-layout)
  sims_mfma<<<dim3(kBH, 3, 16), 256, 0, stream>>>(Qb, K1b, K2b, E1T, E2b, E3f);

  // 4) main contraction (barrier-free) + denominator
  strassen_v3<false><<<dim3(16, 4, kBH), 256, 0, stream>>>(
      E2b, E1T, E3f, V1, V2T, NUMp, DENp);
  strassen_v3<true><<<dim3(1, 4, kBH), 256, 0, stream>>>(
      E2b, E1T, E3f, V1, V2T, NUMp, DENp);

  // 5) normalize + transpose back (bf16 out)
  normalize_attn<<<dim3(1024), 256, 0, stream>>>(NUMp, DENp, atnb);

  // 6) out = attn @ w_out -> d_out (f32)
  gemm_mfma<true><<<dim3(kDIM / 64, kBN / 64), 256, 0, stream>>>(
      atnb, woT, d_out, kBN, kDIM, kDIM);
}

// Round 8
// 199.226 us; speedup vs baseline: 1.2333x; 1.2333x over previous
//
#include <hip/hip_runtime.h>
#include <hip/hip_bf16.h>

// StrassenMHA on MI355X — round 8: deepen MFMA clusters in the main
// contraction (k-half structure: 16 MFMA per 4-load cluster, fold 2x not 4x)
// + fixed denominator kernel (j-split grid + persistent acc + atomics).
// B=2, N=256, DIM=512, H=8, DH=64. Output f32.

namespace {
constexpr int kN = 256, kH = 8, kDH = 64;
constexpr int kBH = 16;
constexpr int kBN = 512;
constexpr int kDIM = 512;
constexpr int kQKV = 2560;
constexpr float kEps = 1.1920928955078125e-07f;

typedef unsigned short u16;
typedef __attribute__((ext_vector_type(8))) short short8v;   // 8 x bf16
typedef __attribute__((ext_vector_type(4))) float float4v;   // mfma acc

// ws layout (float-element offsets); sizes in float-slots
constexpr size_t OF_XB   = 0;                   // 131,072 (xb bf16 512x512)
constexpr size_t OF_WT   = OF_XB   + 131072;    // 655,360 (w_qkvT bf16 2560x512)
constexpr size_t OF_WOT  = OF_WT   + 655360;    // 131,072 (w_outT bf16 512x512)
constexpr size_t OF_QKVB = OF_WOT  + 131072;    // 655,360 (qkv bf16 512x2560)
constexpr size_t OF_QB   = OF_QKVB + 655360;    // 131,072 (Q bf16 16x256x64)
constexpr size_t OF_K1B  = OF_QB   + 131072;    // 131,072
constexpr size_t OF_K2B  = OF_K1B  + 131072;    // 131,072
constexpr size_t OF_V1   = OF_K2B  + 131072;    // 262,144 f32 [bh][n][d]
constexpr size_t OF_V2T  = OF_V1   + 262144;    // 262,144 f32 [bh][d][k]
constexpr size_t OF_E1T  = OF_V2T  + 262144;    // 1,048,576 f32 [bh][j][i]
constexpr size_t OF_E2B  = OF_E1T  + 1048576;   // 524,288 (bf16 [bh][i][k])
constexpr size_t OF_E3F  = OF_E2B  + 524288;    // 524,288 (bf16 frag-layout)
constexpr size_t OF_NUM  = OF_E3F  + 524288;    // 262,144 f32
constexpr size_t OF_DEN  = OF_NUM  + 262144;    //   4,096 f32
constexpr size_t OF_ATNB = OF_DEN  + 4096;      // 131,072 (attn bf16 512x512)
// total = 4,984,832 floats = 19.94 MB
} // namespace

__device__ __forceinline__ unsigned int bf16_rne(float a) {
  unsigned int u = __float_as_uint(a);
  return (u + 0x7fffu + ((u >> 16) & 1u)) >> 16;
}
__device__ __forceinline__ unsigned int pk2_bf16(float a, float b) {
  unsigned int ua = bf16_rne(a);
  unsigned int ub = __float_as_uint(b);
  ub = (ub + 0x7fffu + ((ub >> 16) & 1u)) & 0xffff0000u;
  return ua | ub;
}
__device__ __forceinline__ float bf2f(u16 v) {
  return __uint_as_float(((unsigned)v) << 16);
}

// ------------------------------------------------------------ f32 -> bf16
__global__ __launch_bounds__(256)
void conv_bf16(const float* __restrict__ in, u16* __restrict__ out) {
  const int id = blockIdx.x * 256 + threadIdx.x;
  float4 v = ((const float4*)in)[id];
  ushort4 o;
  o.x = (u16)bf16_rne(v.x); o.y = (u16)bf16_rne(v.y);
  o.z = (u16)bf16_rne(v.z); o.w = (u16)bf16_rne(v.w);
  ((ushort4*)out)[id] = o;
}

// --------------------------------------------- transpose f32 -> bf16
__global__ __launch_bounds__(256)
void transpose_bf16(const float* __restrict__ in, u16* __restrict__ out,
                    int rows, int cols) {
  __shared__ float tile[32][33];
  const int tx = threadIdx.x & 31, ty8 = threadIdx.x >> 5;
  const int c0 = blockIdx.x * 32, r0 = blockIdx.y * 32;
#pragma unroll
  for (int rr = 0; rr < 4; ++rr) {
    int r = ty8 + rr * 8;
    tile[r][tx] = in[(size_t)(r0 + r) * cols + c0 + tx];
  }
  __syncthreads();
#pragma unroll
  for (int rr = 0; rr < 4; ++rr) {
    int r = ty8 + rr * 8;
    out[(size_t)(c0 + r) * rows + r0 + tx] = (u16)bf16_rne(tile[tx][r]);
  }
}

// --------------------------------------------- bf16 MFMA GEMM, frag-direct
template <bool F32OUT>
__global__ __launch_bounds__(256)
void gemm_mfma(const u16* __restrict__ A, const u16* __restrict__ BT,
               void* __restrict__ C, int M, int N, int K) {
  const int t = threadIdx.x, lane = t & 63, w = t >> 6;
  const int lrow = lane & 15, lk = lane >> 4;
  const int m0 = blockIdx.y * 64 + w * 16;
  const int n0 = blockIdx.x * 64;
  float4v acc[4] = {};
#pragma unroll 4
  for (int kk = 0; kk < K; kk += 32) {
    short8v aF = *(const short8v*)(A + (size_t)(m0 + lrow) * K + kk + lk * 8);
#pragma unroll
    for (int n = 0; n < 4; ++n) {
      short8v bF = *(const short8v*)(BT + (size_t)(n0 + n * 16 + lrow) * K + kk + lk * 8);
      acc[n] = __builtin_amdgcn_mfma_f32_16x16x32_bf16(aF, bF, acc[n], 0, 0, 0);
    }
  }
#pragma unroll
  for (int n = 0; n < 4; ++n)
#pragma unroll
    for (int r = 0; r < 4; ++r) {
      const int row = m0 + lk * 4 + r, col = n0 + n * 16 + lrow;
      if (F32OUT) ((float*)C)[(size_t)row * N + col] = acc[n][r];
      else        ((u16*)C)[(size_t)row * N + col] = (u16)bf16_rne(acc[n][r]);
    }
}

// ------------------------------------------------- RMSNorm + head split
__global__ __launch_bounds__(64)
void rms_layout(const u16* __restrict__ qkvb,
                const float* __restrict__ wq, const float* __restrict__ wk1,
                const float* __restrict__ wk2,
                u16* __restrict__ Qb, u16* __restrict__ K1b,
                u16* __restrict__ K2b, float* __restrict__ V1,
                float* __restrict__ V2T) {
  const int bnh = blockIdx.x;
  const int h = bnh & 7;
  const int bn = bnh >> 3;
  const int b = bn >> 8;
  const int d = threadIdx.x;
  const u16* row = qkvb + (size_t)bn * kQKV;
  const int base = h * 64 + d;
  float q  = bf2f(row[0 * 512 + base]);
  float k1 = bf2f(row[1 * 512 + base]);
  float k2 = bf2f(row[2 * 512 + base]);
  float v1 = bf2f(row[3 * 512 + base]);
  float v2 = bf2f(row[4 * 512 + base]);
  float sq = q * q, s1 = k1 * k1, s2 = k2 * k2;
#pragma unroll
  for (int m = 32; m >= 1; m >>= 1) {
    sq += __shfl_xor(sq, m);
    s1 += __shfl_xor(s1, m);
    s2 += __shfl_xor(s2, m);
  }
  const float rq = rsqrtf(sq * (1.0f / 64) + kEps);
  const float r1 = rsqrtf(s1 * (1.0f / 64) + kEps);
  const float r2 = rsqrtf(s2 * (1.0f / 64) + kEps);
  const int bh = b * kH + h;
  const int n = bn & 255;
  const size_t o = ((size_t)bh * kN + n) * kDH + d;
  Qb[o]  = (u16)bf16_rne(q * rq * wq[d]);
  K1b[o] = (u16)bf16_rne(k1 * r1 * wk1[d]);
  K2b[o] = (u16)bf16_rne(k2 * r2 * wk2[d]);
  V1[o] = v1;
  V2T[((size_t)bh * kDH + d) * kN + n] = v2;
}

// --------------------------------- E = exp(clip(dot/8)) via MFMA
// type 0: Q.K1 -> E1T[j][i] (f32, transposed)
// type 1: Q.K2 -> E2b[i][k] (bf16, row-major)
// type 2: K1.K2 -> E3f (bf16, MFMA FRAGMENT layout via LDS repack)
__global__ __launch_bounds__(256)
void sims_mfma(const u16* __restrict__ Qb, const u16* __restrict__ K1b,
               const u16* __restrict__ K2b, float* __restrict__ E1T,
               u16* __restrict__ E2b, u16* __restrict__ E3f) {
  __shared__ __align__(16) u16 Lt[64 * 80];   // 10 KB repack tile (type 2)
  const int bh = blockIdx.x, type = blockIdx.y;
  const int it = blockIdx.z >> 2, jt = blockIdx.z & 3;
  const int t = threadIdx.x, lane = t & 63, w = t >> 6;
  const int lrow = lane & 15, lk = lane >> 4;
  const u16* Ap = (type == 2 ? K1b : Qb) + (size_t)bh * 16384;
  const u16* Bp = (type == 0 ? K1b : K2b) + (size_t)bh * 16384;
  const int i0 = it * 64 + w * 16, j0 = jt * 64;
  float4v acc[4] = {};
#pragma unroll
  for (int kk = 0; kk < 2; ++kk) {
    short8v aF = *(const short8v*)(Ap + (size_t)(i0 + lrow) * 64 + kk * 32 + lk * 8);
#pragma unroll
    for (int n = 0; n < 4; ++n) {
      short8v bF = *(const short8v*)(Bp + (size_t)(j0 + n * 16 + lrow) * 64 + kk * 32 + lk * 8);
      acc[n] = __builtin_amdgcn_mfma_f32_16x16x32_bf16(aF, bF, acc[n], 0, 0, 0);
    }
  }
  if (type == 0) {
    float* Ep = E1T + (size_t)bh * 65536;
#pragma unroll
    for (int n = 0; n < 4; ++n)
#pragma unroll
      for (int r = 0; r < 4; ++r) {
        float s = acc[n][r] * 0.125f;
        s = fminf(fmaxf(s, -40.0f), 40.0f);
        Ep[(size_t)(j0 + n * 16 + lrow) * 256 + i0 + lk * 4 + r] = __expf(s);
      }
  } else if (type == 1) {
    u16* Ep = E2b + (size_t)bh * 65536;
#pragma unroll
    for (int n = 0; n < 4; ++n)
#pragma unroll
      for (int r = 0; r < 4; ++r) {
        float s = acc[n][r] * 0.125f;
        s = fminf(fmaxf(s, -40.0f), 40.0f);
        Ep[(size_t)(i0 + lk * 4 + r) * 256 + j0 + n * 16 + lrow] =
            (u16)bf16_rne(__expf(s));
      }
  } else {
#pragma unroll
    for (int n = 0; n < 4; ++n)
#pragma unroll
      for (int r = 0; r < 4; ++r) {
        float s = acc[n][r] * 0.125f;
        s = fminf(fmaxf(s, -40.0f), 40.0f);
        Lt[(w * 16 + lk * 4 + r) * 80 + n * 16 + lrow] = (u16)bf16_rne(__expf(s));
      }
    __syncthreads();
    u16* Ep = E3f + (size_t)bh * 65536;
#pragma unroll
    for (int ss = 0; ss < 2; ++ss) {
      const int sl = ss * 256 + t;
      const int nn = sl >> 7, sub = (sl >> 6) & 1, ln = sl & 63;
      const int lr = ln & 15, lq = ln >> 4;
      const uint4 v = *(const uint4*)&Lt[(nn * 16 + lr) * 80 + sub * 32 + lq * 8];
      // slot = (rowtile it*4+nn)*8 + (ks=jt)*2 + sub
      const size_t gslot = (size_t)(((it * 4 + nn) * 8 + jt * 2 + sub) * 64 + ln);
      *(uint4*)(Ep + gslot * 8) = v;
    }
  }
}

// ---------------------------------------------------------- main contraction
// num[i,d] = sum_j e1[i,j] v1[j,d] * sum_k (e2[i,k] v2[k,d]) e3[j,k]
// Two 128-k halves: A-frags (4dd x 4sub) built once per half; per (jt,n):
// 4 contiguous bF loads -> 16 MFMA (4 indep dd-chains) -> one fold.
// grid (16, 4, 16): x=dblk, y=iblk, z=bh. 256 thr / 4 waves. No LDS/barriers.
__global__ __launch_bounds__(256)
void strassen_v4(const u16* __restrict__ E2b, const float* __restrict__ E1T,
                 const u16* __restrict__ E3f, const float* __restrict__ V1,
                 const float* __restrict__ V2T, float* __restrict__ NUM) {
  const int dblk = blockIdx.x;
  const int iblk = blockIdx.y;
  const int bh = blockIdx.z;
  const int d0 = dblk * 4;
  const int t = threadIdx.x;
  const int lane = t & 63, w = t >> 6;
  const int lrow = lane & 15, lk = lane >> 4;

  const size_t ebase = (size_t)bh * 65536;
  const u16* e2p = E2b + ebase;
  const float* e1p = E1T + ebase;
  const u16* e3p = E3f + ebase;
  const float* v2p = V2T + ((size_t)bh * kDH + d0) * kN;
  const float* v1p = V1 + (size_t)bh * kN * kDH + d0;

  const int irowA = iblk * 64 + w * 16 + lrow;
  const int irowD = iblk * 64 + w * 16 + lk * 4;

  float p[4][4] = {};

#pragma unroll 1
  for (int kso = 0; kso < 2; ++kso) {
    const int kbase = kso * 128;
    // ---- A fragments for this k-half: e2 * v2 per d, 4 sub-k of 32
    short8v aFd[4][4];   // [dd][s]
#pragma unroll
    for (int s = 0; s < 4; ++s) {
      const int kseg = kbase + s * 32 + lk * 8;
      const short8v araw = *(const short8v*)(e2p + (size_t)irowA * 256 + kseg);
      float af[8];
#pragma unroll
      for (int e = 0; e < 8; ++e) af[e] = bf2f((u16)araw[e]);
#pragma unroll
      for (int dd = 0; dd < 4; ++dd) {
        const float4 va = *(const float4*)(v2p + (size_t)dd * kN + kseg);
        const float4 vb = *(const float4*)(v2p + (size_t)dd * kN + kseg + 4);
        union { short8v s8; uint4 u; } pk;
        pk.u.x = pk2_bf16(af[0] * va.x, af[1] * va.y);
        pk.u.y = pk2_bf16(af[2] * va.z, af[3] * va.w);
        pk.u.z = pk2_bf16(af[4] * vb.x, af[5] * vb.y);
        pk.u.w = pk2_bf16(af[6] * vb.z, af[7] * vb.w);
        aFd[dd][s] = pk.s8;
      }
    }
    // ---- j-tiles: 16 MFMA per (jt,n) cluster, fold once
#pragma unroll 2
    for (int jt = 0; jt < 4; ++jt) {
#pragma unroll
      for (int n = 0; n < 4; ++n) {
        // 4 contiguous slots: base slot = (jt*4+n)*8 + kso*4, stride 512 u16
        const u16* bb = e3p + ((size_t)((jt * 4 + n) * 8 + kso * 4) * 64 + lane) * 8;
        const short8v bF0 = *(const short8v*)(bb + 0 * 512);
        const short8v bF1 = *(const short8v*)(bb + 1 * 512);
        const short8v bF2 = *(const short8v*)(bb + 2 * 512);
        const short8v bF3 = *(const short8v*)(bb + 3 * 512);
        float4v acc4[4] = {};
#pragma unroll
        for (int dd = 0; dd < 4; ++dd) {
          acc4[dd] = __builtin_amdgcn_mfma_f32_16x16x32_bf16(aFd[dd][0], bF0, acc4[dd], 0, 0, 0);
          acc4[dd] = __builtin_amdgcn_mfma_f32_16x16x32_bf16(aFd[dd][1], bF1, acc4[dd], 0, 0, 0);
          acc4[dd] = __builtin_amdgcn_mfma_f32_16x16x32_bf16(aFd[dd][2], bF2, acc4[dd], 0, 0, 0);
          acc4[dd] = __builtin_amdgcn_mfma_f32_16x16x32_bf16(aFd[dd][3], bF3, acc4[dd], 0, 0, 0);
        }
        const int j = jt * 64 + n * 16 + lrow;
        const float4 e4 = *(const float4*)(e1p + (size_t)j * 256 + irowD);
        const float4 v4 = *(const float4*)(v1p + (size_t)j * kDH);
        const float e1f[4] = {e4.x, e4.y, e4.z, e4.w};
        const float v1s[4] = {v4.x, v4.y, v4.z, v4.w};
#pragma unroll
        for (int dd = 0; dd < 4; ++dd)
#pragma unroll
          for (int r = 0; r < 4; ++r)
            p[dd][r] = fmaf(e1f[r] * v1s[dd], acc4[dd][r], p[dd][r]);
      }
    }
  }

  // reduce the 16 j-residues (across lrow lanes)
#pragma unroll
  for (int dd = 0; dd < 4; ++dd)
#pragma unroll
    for (int r = 0; r < 4; ++r) {
      float v = p[dd][r];
      v += __shfl_xor(v, 1);
      v += __shfl_xor(v, 2);
      v += __shfl_xor(v, 4);
      v += __shfl_xor(v, 8);
      p[dd][r] = v;
    }
  if (lrow == 0) {
#pragma unroll
    for (int r = 0; r < 4; ++r)
#pragma unroll
      for (int dd = 0; dd < 4; ++dd)
        NUM[((size_t)bh * kN + irowD + r) * kDH + d0 + dd] = p[dd][r];
  }
}

// ---------------------------------------------------------- denominator
// den[i] = sum_j e1[i,j] * (E2 @ E3^T)[i,j]. grid (4 jblk, 4 iblk, 16 bh),
// acc persistent over all k (zeroed once), atomicAdd partials into DEN.
__global__ __launch_bounds__(256)
void strassen_den(const u16* __restrict__ E2b, const float* __restrict__ E1T,
                  const u16* __restrict__ E3f, float* __restrict__ DEN) {
  const int jblk = blockIdx.x;
  const int iblk = blockIdx.y;
  const int bh = blockIdx.z;
  const int t = threadIdx.x;
  const int lane = t & 63, w = t >> 6;
  const int lrow = lane & 15, lk = lane >> 4;

  const size_t ebase = (size_t)bh * 65536;
  const u16* e2p = E2b + ebase;
  const float* e1p = E1T + ebase;
  const u16* e3p = E3f + ebase;
  const int irowA = iblk * 64 + w * 16 + lrow;
  const int irowD = iblk * 64 + w * 16 + lk * 4;

  float4v acc[4] = {};
#pragma unroll
  for (int s = 0; s < 8; ++s) {
    const short8v aF = *(const short8v*)(e2p + (size_t)irowA * 256 + s * 32 + lk * 8);
#pragma unroll
    for (int n = 0; n < 4; ++n) {
      const short8v bF = *(const short8v*)(
          e3p + ((size_t)(((jblk * 4 + n) * 8 + s) * 64 + lane)) * 8);
      acc[n] = __builtin_amdgcn_mfma_f32_16x16x32_bf16(aF, bF, acc[n], 0, 0, 0);
    }
  }
  float p[4] = {};
#pragma unroll
  for (int n = 0; n < 4; ++n) {
    const int j = jblk * 64 + n * 16 + lrow;
    const float4 e4 = *(const float4*)(e1p + (size_t)j * 256 + irowD);
    p[0] = fmaf(e4.x, acc[n][0], p[0]);
    p[1] = fmaf(e4.y, acc[n][1], p[1]);
    p[2] = fmaf(e4.z, acc[n][2], p[2]);
    p[3] = fmaf(e4.w, acc[n][3], p[3]);
  }
#pragma unroll
  for (int r = 0; r < 4; ++r) {
    float v = p[r];
    v += __shfl_xor(v, 1);
    v += __shfl_xor(v, 2);
    v += __shfl_xor(v, 4);
    v += __shfl_xor(v, 8);
    p[r] = v;
  }
  if (lrow == 0) {
#pragma unroll
    for (int r = 0; r < 4; ++r)
      atomicAdd(&DEN[(size_t)bh * kN + irowD + r], p[r]);
  }
}

// --------------------------------- normalize + head transpose, bf16 out
__global__ __launch_bounds__(256)
void normalize_attn(const float* __restrict__ NUMp, const float* __restrict__ DENp,
                    u16* __restrict__ attnb) {
  const int idx = blockIdx.x * 256 + threadIdx.x;   // [bh][i][d]
  const int d = idx & 63;
  const int i = (idx >> 6) & 255;
  const int bh = idx >> 14;
  const int b = bh >> 3, h = bh & 7;
  const float v = NUMp[idx] / DENp[bh * kN + i];
  attnb[((size_t)(b * kN + i)) * kDIM + h * kDH + d] = (u16)bf16_rne(v);
}

// ----------------------------------------------------------------- launch
extern "C" void kernel_launch(void* const* d_in, const int* in_sizes, int n_in,
                              void* d_out, int out_size, void* d_ws, size_t ws_size,
                              hipStream_t stream) {
  const float* x     = (const float*)d_in[0];
  const float* w_qkv = (const float*)d_in[1];
  const float* w_out = (const float*)d_in[2];
  const float* qw    = (const float*)d_in[3];
  const float* k1w   = (const float*)d_in[4];
  const float* k2w   = (const float*)d_in[5];

  float* ws = (float*)d_ws;
  u16* xb   = (u16*)(ws + OF_XB);
  u16* wT   = (u16*)(ws + OF_WT);
  u16* woT  = (u16*)(ws + OF_WOT);
  u16* qkvb = (u16*)(ws + OF_QKVB);
  u16* Qb   = (u16*)(ws + OF_QB);
  u16* K1b  = (u16*)(ws + OF_K1B);
  u16* K2b  = (u16*)(ws + OF_K2B);
  float* V1 = ws + OF_V1;
  float* V2T = ws + OF_V2T;
  float* E1T = ws + OF_E1T;
  u16* E2b  = (u16*)(ws + OF_E2B);
  u16* E3f  = (u16*)(ws + OF_E3F);
  float* NUMp = ws + OF_NUM;
  float* DENp = ws + OF_DEN;
  u16* atnb = (u16*)(ws + OF_ATNB);

  // zero DEN (atomic accumulator)
  hipMemsetAsync(DENp, 0, 4096 * sizeof(float), stream);

  // 0) dtype prep: x -> bf16; w_qkv, w_out -> transposed bf16
  conv_bf16<<<dim3(kBN * kDIM / 1024), 256, 0, stream>>>(x, xb);
  transpose_bf16<<<dim3(kQKV / 32, kDIM / 32), 256, 0, stream>>>(
      w_qkv, wT, kDIM, kQKV);
  transpose_bf16<<<dim3(kDIM / 32, kDIM / 32), 256, 0, stream>>>(
      w_out, woT, kDIM, kDIM);

  // 1) qkv = x @ w_qkv (bf16 MFMA, bf16 out)
  gemm_mfma<false><<<dim3(kQKV / 64, kBN / 64), 256, 0, stream>>>(
      xb, wT, qkvb, kBN, kQKV, kDIM);

  // 2) rmsnorm + head split (V2 transposed)
  rms_layout<<<dim3(kBN * kH), 64, 0, stream>>>(
      qkvb, qw, k1w, k2w, Qb, K1b, K2b, V1, V2T);

  // 3) E1T (f32,T), E2 (bf16), E3f (bf16 frag-layout)
  sims_mfma<<<dim3(kBH, 3, 16), 256, 0, stream>>>(Qb, K1b, K2b, E1T, E2b, E3f);

  // 4) denominator (fast, j-split) then main contraction
  strassen_den<<<dim3(4, 4, kBH), 256, 0, stream>>>(E2b, E1T, E3f, DENp);
  strassen_v4<<<dim3(16, 4, kBH), 256, 0, stream>>>(
      E2b, E1T, E3f, V1, V2T, NUMp);

  // 5) normalize + transpose back (bf16 out)
  normalize_attn<<<dim3(1024), 256, 0, stream>>>(NUMp, DENp, atnb);

  // 6) out = attn @ w_out -> d_out (f32)
  gemm_mfma<true><<<dim3(kDIM / 64, kBN / 64), 256, 0, stream>>>(
      atnb, woT, d_out, kBN, kDIM, kDIM);
}